// Round 2
// baseline (595.586 us; speedup 1.0000x reference)
//
#include <hip/hip_runtime.h>
#include <math.h>

#define NN 100000
#define EE 1600000
#define ETOT (EE + NN)
#define NB 391  // ceil(NN/256)

__device__ __forceinline__ unsigned short f2bf(float f) {
  unsigned int u = __float_as_uint(f);
  u = u + 0x7fffu + ((u >> 16) & 1u);  // RNE
  return (unsigned short)(u >> 16);
}

// WA[k][h] = sum_c W[k][ (h&3)*32 + c ] * att[(h&3)][c]   (h<4: att_src, h>=4: att_dst)
__global__ void k_wa(const float* __restrict__ W, const float* __restrict__ asrc,
                     const float* __restrict__ adst, float* __restrict__ WA) {
  int t = blockIdx.x * 256 + threadIdx.x;
  if (t >= 1024) return;
  int k = t >> 3, h = t & 7, hh = h & 3;
  const float* att = (h < 4) ? asrc : adst;
  float s = 0.f;
#pragma unroll
  for (int c = 0; c < 32; c++) s += W[k * 128 + hh * 32 + c] * att[hh * 32 + c];
  WA[k * 8 + h] = s;
}

// xw = x @ W  (W staged bf16 in LDS), plus a[node][0..7] = x @ WA (fp32)
__global__ __launch_bounds__(256) void k_gemm(const float* __restrict__ x,
                                              const float* __restrict__ W,
                                              const float* __restrict__ WA,
                                              float* __restrict__ xw,
                                              float* __restrict__ a) {
  __shared__ unsigned short Wl[16384];  // bf16 bits, [k][c]
  __shared__ float WAl[1024];           // [k][h]
  int tid = threadIdx.x;
  for (int i = tid; i < 16384; i += 256) Wl[i] = f2bf(W[i]);
  for (int i = tid; i < 1024; i += 256) WAl[i] = WA[i];
  __syncthreads();

  int r0 = blockIdx.x * 64 + (tid >> 4) * 4;  // 4 rows per thread
  int c0 = (tid & 15) * 8;                    // 8 cols per thread
  float acc[4][8];
#pragma unroll
  for (int i = 0; i < 4; i++)
#pragma unroll
    for (int j = 0; j < 8; j++) acc[i][j] = 0.f;

  for (int kc = 0; kc < 32; ++kc) {  // 4 k per chunk
    float xs[4][4];
#pragma unroll
    for (int i = 0; i < 4; i++) {
      int r = r0 + i;
      float4 v = (r < NN) ? ((const float4*)x)[(size_t)r * 32 + kc]
                          : make_float4(0.f, 0.f, 0.f, 0.f);
      xs[i][0] = v.x; xs[i][1] = v.y; xs[i][2] = v.z; xs[i][3] = v.w;
    }
#pragma unroll
    for (int q = 0; q < 4; q++) {
      int k = kc * 4 + q;
      uint4 wv = *((const uint4*)&Wl[k * 128 + c0]);
      float wf[8];
      wf[0] = __uint_as_float(wv.x << 16); wf[1] = __uint_as_float(wv.x & 0xffff0000u);
      wf[2] = __uint_as_float(wv.y << 16); wf[3] = __uint_as_float(wv.y & 0xffff0000u);
      wf[4] = __uint_as_float(wv.z << 16); wf[5] = __uint_as_float(wv.z & 0xffff0000u);
      wf[6] = __uint_as_float(wv.w << 16); wf[7] = __uint_as_float(wv.w & 0xffff0000u);
#pragma unroll
      for (int i = 0; i < 4; i++)
#pragma unroll
        for (int j = 0; j < 8; j++) acc[i][j] = fmaf(xs[i][q], wf[j], acc[i][j]);
    }
  }
#pragma unroll
  for (int i = 0; i < 4; i++) {
    int r = r0 + i;
    if (r < NN) {
      float4 o0 = make_float4(acc[i][0], acc[i][1], acc[i][2], acc[i][3]);
      float4 o1 = make_float4(acc[i][4], acc[i][5], acc[i][6], acc[i][7]);
      ((float4*)(xw + (size_t)r * 128 + c0))[0] = o0;
      ((float4*)(xw + (size_t)r * 128 + c0))[1] = o1;
    }
  }
  // attention logits: a[r][h] = x[r] . WA[:,h], fp32
  int h = tid & 15;
  if (h < 8) {
    float aa[4] = {0.f, 0.f, 0.f, 0.f};
    for (int kc = 0; kc < 32; ++kc) {
#pragma unroll
      for (int i = 0; i < 4; i++) {
        int r = r0 + i;
        float4 v = (r < NN) ? ((const float4*)x)[(size_t)r * 32 + kc]
                            : make_float4(0.f, 0.f, 0.f, 0.f);
        aa[i] = fmaf(v.x, WAl[(kc * 4 + 0) * 8 + h], aa[i]);
        aa[i] = fmaf(v.y, WAl[(kc * 4 + 1) * 8 + h], aa[i]);
        aa[i] = fmaf(v.z, WAl[(kc * 4 + 2) * 8 + h], aa[i]);
        aa[i] = fmaf(v.w, WAl[(kc * 4 + 3) * 8 + h], aa[i]);
      }
    }
#pragma unroll
    for (int i = 0; i < 4; i++) {
      int r = r0 + i;
      if (r < NN) a[(size_t)r * 8 + h] = aa[i];
    }
  }
}

__global__ void k_init(int* __restrict__ deg) {
  int i = blockIdx.x * 256 + threadIdx.x;
  if (i < NN) deg[i] = 1;  // self-loop pre-counted
}

__global__ void k_count(const int* __restrict__ ei, int* __restrict__ deg) {
  int t = blockIdx.x * 256 + threadIdx.x;
  if (t < EE) {
    int dd = ei[(size_t)EE + t];
    atomicAdd(&deg[dd], 1);
  }
}

__global__ void k_scan1(const int* __restrict__ deg, int* __restrict__ offs,
                        int* __restrict__ bsum) {
  __shared__ int s[256];
  int t = threadIdx.x;
  int i = blockIdx.x * 256 + t;
  int v = (i < NN) ? deg[i] : 0;
  s[t] = v;
  __syncthreads();
  for (int off = 1; off < 256; off <<= 1) {
    int tmp = (t >= off) ? s[t - off] : 0;
    __syncthreads();
    s[t] += tmp;
    __syncthreads();
  }
  if (i < NN) offs[i + 1] = s[t];
  if (t == 255) bsum[blockIdx.x] = s[255];
}

__global__ void k_scan2(const int* __restrict__ bsum, int* __restrict__ pb) {
  __shared__ int s[512];
  int t = threadIdx.x;
  int v = (t < NB) ? bsum[t] : 0;
  s[t] = v;
  __syncthreads();
  for (int off = 1; off < 512; off <<= 1) {
    int tmp = (t >= off) ? s[t - off] : 0;
    __syncthreads();
    s[t] += tmp;
    __syncthreads();
  }
  if (t < NB) pb[t] = s[t] - v;  // exclusive prefix of block sums
}

__global__ void k_scan3(const int* __restrict__ deg, const int* __restrict__ pb,
                        int* __restrict__ offs, int* __restrict__ cursor) {
  int t = threadIdx.x, b = blockIdx.x;
  int i = b * 256 + t;
  if (i == 0) offs[0] = 0;
  if (i < NN) {
    int v = offs[i + 1] + pb[b];
    offs[i + 1] = v;          // final inclusive -> offs[i+1]
    cursor[i] = v - deg[i];   // exclusive start
  }
}

__global__ void k_scatter(const int* __restrict__ ei, int* __restrict__ cursor,
                          int* __restrict__ es) {
  int t = blockIdx.x * 256 + threadIdx.x;
  if (t >= ETOT) return;
  int s, dd;
  if (t < EE) {
    s = ei[t];
    dd = ei[(size_t)EE + t];
  } else {
    s = t - EE;
    dd = s;
  }
  int pos = atomicAdd(&cursor[dd], 1);
  es[pos] = s;
}

// one wave per destination node: softmax over incoming edges + weighted sum + LayerNorm
__global__ __launch_bounds__(256) void k_agg(const float* __restrict__ xw,
                                             const float* __restrict__ a,
                                             const int* __restrict__ offs,
                                             const int* __restrict__ es,
                                             const float* __restrict__ bias,
                                             const float* __restrict__ gamma,
                                             const float* __restrict__ beta,
                                             float* __restrict__ out) {
  int lane = threadIdx.x & 63;
  int node = blockIdx.x * 4 + (threadIdx.x >> 6);
  if (node >= NN) return;
  int off0 = offs[node], off1 = offs[node + 1];
  int d = off1 - off0;
  float4 ad = *((const float4*)(a + (size_t)node * 8 + 4));

  // pass 1: max per head
  float mx0 = -1e30f, mx1 = -1e30f, mx2 = -1e30f, mx3 = -1e30f;
  for (int jj = lane; jj < d; jj += 64) {
    int s = es[off0 + jj];
    float4 av = *((const float4*)(a + (size_t)s * 8));
    float e0 = av.x + ad.x; e0 = (e0 > 0.f) ? e0 : 0.2f * e0;
    float e1 = av.y + ad.y; e1 = (e1 > 0.f) ? e1 : 0.2f * e1;
    float e2 = av.z + ad.z; e2 = (e2 > 0.f) ? e2 : 0.2f * e2;
    float e3 = av.w + ad.w; e3 = (e3 > 0.f) ? e3 : 0.2f * e3;
    mx0 = fmaxf(mx0, e0); mx1 = fmaxf(mx1, e1);
    mx2 = fmaxf(mx2, e2); mx3 = fmaxf(mx3, e3);
  }
#pragma unroll
  for (int o = 32; o; o >>= 1) {
    mx0 = fmaxf(mx0, __shfl_xor(mx0, o));
    mx1 = fmaxf(mx1, __shfl_xor(mx1, o));
    mx2 = fmaxf(mx2, __shfl_xor(mx2, o));
    mx3 = fmaxf(mx3, __shfl_xor(mx3, o));
  }
  // pass 2: sum of exp
  float se0 = 0.f, se1 = 0.f, se2 = 0.f, se3 = 0.f;
  for (int jj = lane; jj < d; jj += 64) {
    int s = es[off0 + jj];
    float4 av = *((const float4*)(a + (size_t)s * 8));
    float e0 = av.x + ad.x; e0 = (e0 > 0.f) ? e0 : 0.2f * e0;
    float e1 = av.y + ad.y; e1 = (e1 > 0.f) ? e1 : 0.2f * e1;
    float e2 = av.z + ad.z; e2 = (e2 > 0.f) ? e2 : 0.2f * e2;
    float e3 = av.w + ad.w; e3 = (e3 > 0.f) ? e3 : 0.2f * e3;
    se0 += __expf(e0 - mx0); se1 += __expf(e1 - mx1);
    se2 += __expf(e2 - mx2); se3 += __expf(e3 - mx3);
  }
#pragma unroll
  for (int o = 32; o; o >>= 1) {
    se0 += __shfl_xor(se0, o); se1 += __shfl_xor(se1, o);
    se2 += __shfl_xor(se2, o); se3 += __shfl_xor(se3, o);
  }
  float r0 = 1.f / (se0 + 1e-16f), r1 = 1.f / (se1 + 1e-16f);
  float r2 = 1.f / (se2 + 1e-16f), r3 = 1.f / (se3 + 1e-16f);

  // pass 3: weighted accumulate; lane owns channels c, c+1 (same head)
  int c = lane * 2;
  float accx = 0.f, accy = 0.f;
  for (int base = 0; base < d; base += 64) {
    int jj = base + lane;
    int sl = 0;
    float ex0 = 0.f, ex1 = 0.f, ex2 = 0.f, ex3 = 0.f;
    if (jj < d) {
      sl = es[off0 + jj];
      float4 av = *((const float4*)(a + (size_t)sl * 8));
      float e0 = av.x + ad.x; e0 = (e0 > 0.f) ? e0 : 0.2f * e0; ex0 = __expf(e0 - mx0) * r0;
      float e1 = av.y + ad.y; e1 = (e1 > 0.f) ? e1 : 0.2f * e1; ex1 = __expf(e1 - mx1) * r1;
      float e2 = av.z + ad.z; e2 = (e2 > 0.f) ? e2 : 0.2f * e2; ex2 = __expf(e2 - mx2) * r2;
      float e3 = av.w + ad.w; e3 = (e3 > 0.f) ? e3 : 0.2f * e3; ex3 = __expf(e3 - mx3) * r3;
    }
    int cnt = (d - base < 64) ? (d - base) : 64;
    for (int j = 0; j < cnt; ++j) {
      int sj = __shfl(sl, j);
      float w0 = __shfl(ex0, j), w1 = __shfl(ex1, j);
      float w2 = __shfl(ex2, j), w3 = __shfl(ex3, j);
      float wl = (lane & 32) ? ((lane & 16) ? w3 : w2) : ((lane & 16) ? w1 : w0);
      float2 xv = *((const float2*)(xw + (size_t)sj * 128 + c));
      accx = fmaf(wl, xv.x, accx);
      accy = fmaf(wl, xv.y, accy);
    }
  }
  // LayerNorm epilogue
  float vx = accx + bias[c];
  float vy = accy + bias[c + 1];
  float sum = vx + vy, sq = vx * vx + vy * vy;
#pragma unroll
  for (int o = 32; o; o >>= 1) {
    sum += __shfl_xor(sum, o);
    sq += __shfl_xor(sq, o);
  }
  float mean = sum * (1.f / 128.f);
  float var = sq * (1.f / 128.f) - mean * mean;
  float rs = rsqrtf(var + 1e-5f);
  float o0 = gamma[c] * (vx - mean) * rs + beta[c];
  float o1 = gamma[c + 1] * (vy - mean) * rs + beta[c + 1];
  float2 ov; ov.x = o0; ov.y = o1;
  *((float2*)(out + (size_t)node * 128 + c)) = ov;
}

extern "C" void kernel_launch(void* const* d_in, const int* in_sizes, int n_in,
                              void* d_out, int out_size, void* d_ws, size_t ws_size,
                              hipStream_t stream) {
  const float* x = (const float*)d_in[0];
  const int* ei = (const int*)d_in[1];  // harness passes integer inputs as int32
  // d_in[2] edge_weight: unused by reference
  const float* W = (const float*)d_in[3];
  const float* att_src = (const float*)d_in[4];
  const float* att_dst = (const float*)d_in[5];
  const float* bias = (const float*)d_in[6];
  const float* gamma = (const float*)d_in[7];
  const float* beta = (const float*)d_in[8];
  float* out = (float*)d_out;

  char* p = (char*)d_ws;
  auto alloc = [&](size_t bytes) -> char* {
    char* r = p;
    p += (bytes + 255) & ~(size_t)255;
    return r;
  };
  float* xw = (float*)alloc((size_t)NN * 128 * 4);  // 51.2 MB
  float* a = (float*)alloc((size_t)NN * 8 * 4);     // 3.2 MB  [a_src(4), a_dst(4)]
  float* WA = (float*)alloc(1024 * 4);
  int* deg = (int*)alloc((size_t)NN * 4);
  int* offs = (int*)alloc((size_t)(NN + 1) * 4);
  int* cursor = (int*)alloc((size_t)NN * 4);
  int* bsum = (int*)alloc(512 * 4);
  int* pb = (int*)alloc(512 * 4);
  int* es = (int*)alloc((size_t)ETOT * 4);          // 6.8 MB

  k_wa<<<4, 256, 0, stream>>>(W, att_src, att_dst, WA);
  k_gemm<<<(NN + 63) / 64, 256, 0, stream>>>(x, W, WA, xw, a);
  k_init<<<(NN + 255) / 256, 256, 0, stream>>>(deg);
  k_count<<<(EE + 255) / 256, 256, 0, stream>>>(ei, deg);
  k_scan1<<<NB, 256, 0, stream>>>(deg, offs, bsum);
  k_scan2<<<1, 512, 0, stream>>>(bsum, pb);
  k_scan3<<<NB, 256, 0, stream>>>(deg, pb, offs, cursor);
  k_scatter<<<(ETOT + 255) / 256, 256, 0, stream>>>(ei, cursor, es);
  k_agg<<<NN / 4, 256, 0, stream>>>(xw, a, offs, es, bias, gamma, beta, out);
}

// Round 3
// 542.225 us; speedup vs baseline: 1.0984x; 1.0984x over previous
//
#include <hip/hip_runtime.h>
#include <math.h>

#define NN 100000
#define EE 1600000
#define ETOT (EE + NN)
#define NB 391  // ceil(NN/256)

__device__ __forceinline__ unsigned short f2bf(float f) {
  unsigned int u = __float_as_uint(f);
  u = u + 0x7fffu + ((u >> 16) & 1u);  // RNE
  return (unsigned short)(u >> 16);
}

// xw(bf16) = x @ W  (W staged bf16 in LDS); attention logits a[r][0..7] from the
// accumulator via cross-lane reduction (a_src h<4, a_dst h>=4).
__global__ __launch_bounds__(256) void k_gemm(const float* __restrict__ x,
                                              const float* __restrict__ W,
                                              const float* __restrict__ att_src,
                                              const float* __restrict__ att_dst,
                                              unsigned short* __restrict__ xwb,
                                              float* __restrict__ a) {
  __shared__ unsigned short Wl[16384];  // bf16 bits, [k][c]
  int tid = threadIdx.x;
  for (int i = tid; i < 16384; i += 256) Wl[i] = f2bf(W[i]);
  __syncthreads();

  int r0 = blockIdx.x * 64 + (tid >> 4) * 4;  // 4 rows per thread
  int c0 = (tid & 15) * 8;                    // 8 cols per thread (within one head)
  float acc[4][8];
#pragma unroll
  for (int i = 0; i < 4; i++)
#pragma unroll
    for (int j = 0; j < 8; j++) acc[i][j] = 0.f;

  for (int kc = 0; kc < 32; ++kc) {  // 4 k per chunk
    float xs[4][4];
#pragma unroll
    for (int i = 0; i < 4; i++) {
      int r = r0 + i;
      float4 v = (r < NN) ? ((const float4*)x)[(size_t)r * 32 + kc]
                          : make_float4(0.f, 0.f, 0.f, 0.f);
      xs[i][0] = v.x; xs[i][1] = v.y; xs[i][2] = v.z; xs[i][3] = v.w;
    }
#pragma unroll
    for (int q = 0; q < 4; q++) {
      int k = kc * 4 + q;
      uint4 wv = *((const uint4*)&Wl[k * 128 + c0]);
      float wf[8];
      wf[0] = __uint_as_float(wv.x << 16); wf[1] = __uint_as_float(wv.x & 0xffff0000u);
      wf[2] = __uint_as_float(wv.y << 16); wf[3] = __uint_as_float(wv.y & 0xffff0000u);
      wf[4] = __uint_as_float(wv.z << 16); wf[5] = __uint_as_float(wv.z & 0xffff0000u);
      wf[6] = __uint_as_float(wv.w << 16); wf[7] = __uint_as_float(wv.w & 0xffff0000u);
#pragma unroll
      for (int i = 0; i < 4; i++)
#pragma unroll
        for (int j = 0; j < 8; j++) acc[i][j] = fmaf(xs[i][q], wf[j], acc[i][j]);
    }
  }

  // attention partials: this thread's 8 channels live in head h = (tid&15)>>2
  float as8[8], ad8[8];
#pragma unroll
  for (int j = 0; j < 8; j++) {
    as8[j] = att_src[c0 + j];  // (H,C) flat == channel index
    ad8[j] = att_dst[c0 + j];
  }
#pragma unroll
  for (int i = 0; i < 4; i++) {
    int r = r0 + i;
    float ps = 0.f, pd = 0.f;
#pragma unroll
    for (int j = 0; j < 8; j++) {
      ps = fmaf(acc[i][j], as8[j], ps);
      pd = fmaf(acc[i][j], ad8[j], pd);
    }
    ps += __shfl_xor(ps, 1); ps += __shfl_xor(ps, 2);
    pd += __shfl_xor(pd, 1); pd += __shfl_xor(pd, 2);
    if (r < NN) {
      if ((tid & 3) == 0) {
        int h = (tid & 15) >> 2;
        a[(size_t)r * 8 + h] = ps;
        a[(size_t)r * 8 + 4 + h] = pd;
      }
      uint4 o;
      o.x = (unsigned)f2bf(acc[i][0]) | ((unsigned)f2bf(acc[i][1]) << 16);
      o.y = (unsigned)f2bf(acc[i][2]) | ((unsigned)f2bf(acc[i][3]) << 16);
      o.z = (unsigned)f2bf(acc[i][4]) | ((unsigned)f2bf(acc[i][5]) << 16);
      o.w = (unsigned)f2bf(acc[i][6]) | ((unsigned)f2bf(acc[i][7]) << 16);
      *((uint4*)(xwb + (size_t)r * 128 + c0)) = o;
    }
  }
}

__global__ void k_init(int* __restrict__ deg) {
  int i = blockIdx.x * 256 + threadIdx.x;
  if (i < NN) deg[i] = 1;  // self-loop pre-counted
}

__global__ void k_count(const int* __restrict__ ei, int* __restrict__ deg) {
  int t = blockIdx.x * 256 + threadIdx.x;
  if (t < EE) {
    int dd = ei[(size_t)EE + t];
    atomicAdd(&deg[dd], 1);
  }
}

__global__ void k_scan1(const int* __restrict__ deg, int* __restrict__ offs,
                        int* __restrict__ bsum) {
  __shared__ int s[256];
  int t = threadIdx.x;
  int i = blockIdx.x * 256 + t;
  int v = (i < NN) ? deg[i] : 0;
  s[t] = v;
  __syncthreads();
  for (int off = 1; off < 256; off <<= 1) {
    int tmp = (t >= off) ? s[t - off] : 0;
    __syncthreads();
    s[t] += tmp;
    __syncthreads();
  }
  if (i < NN) offs[i + 1] = s[t];
  if (t == 255) bsum[blockIdx.x] = s[255];
}

__global__ void k_scan2(const int* __restrict__ bsum, int* __restrict__ pb) {
  __shared__ int s[512];
  int t = threadIdx.x;
  int v = (t < NB) ? bsum[t] : 0;
  s[t] = v;
  __syncthreads();
  for (int off = 1; off < 512; off <<= 1) {
    int tmp = (t >= off) ? s[t - off] : 0;
    __syncthreads();
    s[t] += tmp;
    __syncthreads();
  }
  if (t < NB) pb[t] = s[t] - v;  // exclusive prefix of block sums
}

__global__ void k_scan3(const int* __restrict__ deg, const int* __restrict__ pb,
                        int* __restrict__ offs, int* __restrict__ cursor) {
  int t = threadIdx.x, b = blockIdx.x;
  int i = b * 256 + t;
  if (i == 0) offs[0] = 0;
  if (i < NN) {
    int v = offs[i + 1] + pb[b];
    offs[i + 1] = v;          // final inclusive -> offs[i+1]
    cursor[i] = v - deg[i];   // exclusive start
  }
}

__global__ void k_scatter(const int* __restrict__ ei, int* __restrict__ cursor,
                          int* __restrict__ es) {
  int t = blockIdx.x * 256 + threadIdx.x;
  if (t >= ETOT) return;
  int s, dd;
  if (t < EE) {
    s = ei[t];
    dd = ei[(size_t)EE + t];
  } else {
    s = t - EE;
    dd = s;
  }
  int pos = atomicAdd(&cursor[dd], 1);
  es[pos] = s;
}

// one wave per destination node, SINGLE pass:
// out = (sum_j exp(e_j) * xw[src_j]) / sum_j exp(e_j), then LayerNorm.
__global__ __launch_bounds__(256) void k_agg(const unsigned short* __restrict__ xwb,
                                             const float* __restrict__ a,
                                             const int* __restrict__ offs,
                                             const int* __restrict__ es,
                                             const float* __restrict__ bias,
                                             const float* __restrict__ gamma,
                                             const float* __restrict__ beta,
                                             float* __restrict__ out) {
  int lane = threadIdx.x & 63;
  int node = blockIdx.x * 4 + (threadIdx.x >> 6);
  int off0 = offs[node], off1 = offs[node + 1];
  int d = off1 - off0;
  float4 ad = *((const float4*)(a + (size_t)node * 8 + 4));

  int c = lane * 2;  // this lane's two channels (same head: h = lane>>4)
  float se0 = 0.f, se1 = 0.f, se2 = 0.f, se3 = 0.f;
  float accx = 0.f, accy = 0.f;
  const unsigned* xp = (const unsigned*)xwb + lane;  // +sj*64 dwords per edge

  for (int base = 0; base < d; base += 64) {
    int jj = base + lane;
    int sl = 0;
    float ex0 = 0.f, ex1 = 0.f, ex2 = 0.f, ex3 = 0.f;
    if (jj < d) {
      sl = es[off0 + jj];
      float4 av = *((const float4*)(a + (size_t)sl * 8));
      float e0 = av.x + ad.x; e0 = (e0 > 0.f) ? e0 : 0.2f * e0; ex0 = __expf(e0);
      float e1 = av.y + ad.y; e1 = (e1 > 0.f) ? e1 : 0.2f * e1; ex1 = __expf(e1);
      float e2 = av.z + ad.z; e2 = (e2 > 0.f) ? e2 : 0.2f * e2; ex2 = __expf(e2);
      float e3 = av.w + ad.w; e3 = (e3 > 0.f) ? e3 : 0.2f * e3; ex3 = __expf(e3);
    }
    se0 += ex0; se1 += ex1; se2 += ex2; se3 += ex3;
    int cnt = (d - base < 64) ? (d - base) : 64;
    for (int j = 0; j < cnt; ++j) {
      int sj = __shfl(sl, j);
      float w0 = __shfl(ex0, j), w1 = __shfl(ex1, j);
      float w2 = __shfl(ex2, j), w3 = __shfl(ex3, j);
      float wl = (lane & 32) ? ((lane & 16) ? w3 : w2) : ((lane & 16) ? w1 : w0);
      unsigned uv = xp[(unsigned)sj * 64u];  // 2 bf16 channels, 4B/lane coalesced
      accx = fmaf(wl, __uint_as_float(uv << 16), accx);
      accy = fmaf(wl, __uint_as_float(uv & 0xffff0000u), accy);
    }
  }
  // reduce sum-exp across the wave, pick this lane's head
#pragma unroll
  for (int o = 32; o; o >>= 1) {
    se0 += __shfl_xor(se0, o); se1 += __shfl_xor(se1, o);
    se2 += __shfl_xor(se2, o); se3 += __shfl_xor(se3, o);
  }
  float sh = (lane & 32) ? ((lane & 16) ? se3 : se2) : ((lane & 16) ? se1 : se0);
  float rn = 1.f / (sh + 1e-16f);

  // LayerNorm epilogue
  float vx = accx * rn + bias[c];
  float vy = accy * rn + bias[c + 1];
  float sum = vx + vy, sq = vx * vx + vy * vy;
#pragma unroll
  for (int o = 32; o; o >>= 1) {
    sum += __shfl_xor(sum, o);
    sq += __shfl_xor(sq, o);
  }
  float mean = sum * (1.f / 128.f);
  float var = sq * (1.f / 128.f) - mean * mean;
  float rs = rsqrtf(var + 1e-5f);
  float o0 = gamma[c] * (vx - mean) * rs + beta[c];
  float o1 = gamma[c + 1] * (vy - mean) * rs + beta[c + 1];
  float2 ov; ov.x = o0; ov.y = o1;
  *((float2*)(out + (size_t)node * 128 + c)) = ov;
}

extern "C" void kernel_launch(void* const* d_in, const int* in_sizes, int n_in,
                              void* d_out, int out_size, void* d_ws, size_t ws_size,
                              hipStream_t stream) {
  const float* x = (const float*)d_in[0];
  const int* ei = (const int*)d_in[1];  // harness passes integer inputs as int32
  // d_in[2] edge_weight: unused by reference
  const float* W = (const float*)d_in[3];
  const float* att_src = (const float*)d_in[4];
  const float* att_dst = (const float*)d_in[5];
  const float* bias = (const float*)d_in[6];
  const float* gamma = (const float*)d_in[7];
  const float* beta = (const float*)d_in[8];
  float* out = (float*)d_out;

  char* p = (char*)d_ws;
  auto alloc = [&](size_t bytes) -> char* {
    char* r = p;
    p += (bytes + 255) & ~(size_t)255;
    return r;
  };
  unsigned short* xwb = (unsigned short*)alloc((size_t)NN * 128 * 2);  // 25.6 MB bf16
  float* a = (float*)alloc((size_t)NN * 8 * 4);                        // 3.2 MB
  int* deg = (int*)alloc((size_t)NN * 4);
  int* offs = (int*)alloc((size_t)(NN + 1) * 4);
  int* cursor = (int*)alloc((size_t)NN * 4);
  int* bsum = (int*)alloc(512 * 4);
  int* pb = (int*)alloc(512 * 4);
  int* es = (int*)alloc((size_t)ETOT * 4);                             // 6.8 MB

  k_gemm<<<(NN + 63) / 64, 256, 0, stream>>>(x, W, att_src, att_dst, xwb, a);
  k_init<<<(NN + 255) / 256, 256, 0, stream>>>(deg);
  k_count<<<(EE + 255) / 256, 256, 0, stream>>>(ei, deg);
  k_scan1<<<NB, 256, 0, stream>>>(deg, offs, bsum);
  k_scan2<<<1, 512, 0, stream>>>(bsum, pb);
  k_scan3<<<NB, 256, 0, stream>>>(deg, pb, offs, cursor);
  k_scatter<<<(ETOT + 255) / 256, 256, 0, stream>>>(ei, cursor, es);
  k_agg<<<NN / 4, 256, 0, stream>>>(xwb, a, offs, es, bias, gamma, beta, out);
}

// Round 4
// 524.609 us; speedup vs baseline: 1.1353x; 1.0336x over previous
//
#include <hip/hip_runtime.h>
#include <math.h>

#define NN 100000
#define EE 1600000
#define ETOT (EE + NN)
#define NB 391  // ceil(NN/256)

__device__ __forceinline__ unsigned short f2bf(float f) {
  unsigned int u = __float_as_uint(f);
  u = u + 0x7fffu + ((u >> 16) & 1u);  // RNE
  return (unsigned short)(u >> 16);
}

// xw(bf16) = x @ W  (W staged bf16 in LDS); attention logits a[r][0..7] from the
// accumulator via cross-lane reduction (a_src h<4, a_dst h>=4).
__global__ __launch_bounds__(256) void k_gemm(const float* __restrict__ x,
                                              const float* __restrict__ W,
                                              const float* __restrict__ att_src,
                                              const float* __restrict__ att_dst,
                                              unsigned short* __restrict__ xwb,
                                              float* __restrict__ a) {
  __shared__ unsigned short Wl[16384];  // bf16 bits, [k][c]
  int tid = threadIdx.x;
  for (int i = tid; i < 16384; i += 256) Wl[i] = f2bf(W[i]);
  __syncthreads();

  int r0 = blockIdx.x * 64 + (tid >> 4) * 4;  // 4 rows per thread
  int c0 = (tid & 15) * 8;                    // 8 cols per thread (within one head)
  float acc[4][8];
#pragma unroll
  for (int i = 0; i < 4; i++)
#pragma unroll
    for (int j = 0; j < 8; j++) acc[i][j] = 0.f;

  for (int kc = 0; kc < 32; ++kc) {  // 4 k per chunk
    float xs[4][4];
#pragma unroll
    for (int i = 0; i < 4; i++) {
      int r = r0 + i;
      float4 v = (r < NN) ? ((const float4*)x)[(size_t)r * 32 + kc]
                          : make_float4(0.f, 0.f, 0.f, 0.f);
      xs[i][0] = v.x; xs[i][1] = v.y; xs[i][2] = v.z; xs[i][3] = v.w;
    }
#pragma unroll
    for (int q = 0; q < 4; q++) {
      int k = kc * 4 + q;
      uint4 wv = *((const uint4*)&Wl[k * 128 + c0]);
      float wf[8];
      wf[0] = __uint_as_float(wv.x << 16); wf[1] = __uint_as_float(wv.x & 0xffff0000u);
      wf[2] = __uint_as_float(wv.y << 16); wf[3] = __uint_as_float(wv.y & 0xffff0000u);
      wf[4] = __uint_as_float(wv.z << 16); wf[5] = __uint_as_float(wv.z & 0xffff0000u);
      wf[6] = __uint_as_float(wv.w << 16); wf[7] = __uint_as_float(wv.w & 0xffff0000u);
#pragma unroll
      for (int i = 0; i < 4; i++)
#pragma unroll
        for (int j = 0; j < 8; j++) acc[i][j] = fmaf(xs[i][q], wf[j], acc[i][j]);
    }
  }

  // attention partials: this thread's 8 channels live in head h = (tid&15)>>2
  float as8[8], ad8[8];
#pragma unroll
  for (int j = 0; j < 8; j++) {
    as8[j] = att_src[c0 + j];  // (H,C) flat == channel index
    ad8[j] = att_dst[c0 + j];
  }
#pragma unroll
  for (int i = 0; i < 4; i++) {
    int r = r0 + i;
    float ps = 0.f, pd = 0.f;
#pragma unroll
    for (int j = 0; j < 8; j++) {
      ps = fmaf(acc[i][j], as8[j], ps);
      pd = fmaf(acc[i][j], ad8[j], pd);
    }
    ps += __shfl_xor(ps, 1); ps += __shfl_xor(ps, 2);
    pd += __shfl_xor(pd, 1); pd += __shfl_xor(pd, 2);
    if (r < NN) {
      if ((tid & 3) == 0) {
        int h = (tid & 15) >> 2;
        a[(size_t)r * 8 + h] = ps;
        a[(size_t)r * 8 + 4 + h] = pd;
      }
      uint4 o;
      o.x = (unsigned)f2bf(acc[i][0]) | ((unsigned)f2bf(acc[i][1]) << 16);
      o.y = (unsigned)f2bf(acc[i][2]) | ((unsigned)f2bf(acc[i][3]) << 16);
      o.z = (unsigned)f2bf(acc[i][4]) | ((unsigned)f2bf(acc[i][5]) << 16);
      o.w = (unsigned)f2bf(acc[i][6]) | ((unsigned)f2bf(acc[i][7]) << 16);
      *((uint4*)(xwb + (size_t)r * 128 + c0)) = o;
    }
  }
}

__global__ void k_init(int* __restrict__ deg) {
  int i = blockIdx.x * 256 + threadIdx.x;
  if (i < NN) deg[i] = 1;  // self-loop pre-counted
}

__global__ void k_count(const int* __restrict__ ei, int* __restrict__ deg) {
  int t = blockIdx.x * 256 + threadIdx.x;
  if (t < EE) {
    int dd = ei[(size_t)EE + t];
    atomicAdd(&deg[dd], 1);
  }
}

__global__ void k_scan1(const int* __restrict__ deg, int* __restrict__ offs,
                        int* __restrict__ bsum) {
  __shared__ int s[256];
  int t = threadIdx.x;
  int i = blockIdx.x * 256 + t;
  int v = (i < NN) ? deg[i] : 0;
  s[t] = v;
  __syncthreads();
  for (int off = 1; off < 256; off <<= 1) {
    int tmp = (t >= off) ? s[t - off] : 0;
    __syncthreads();
    s[t] += tmp;
    __syncthreads();
  }
  if (i < NN) offs[i + 1] = s[t];
  if (t == 255) bsum[blockIdx.x] = s[255];
}

__global__ void k_scan2(const int* __restrict__ bsum, int* __restrict__ pb) {
  __shared__ int s[512];
  int t = threadIdx.x;
  int v = (t < NB) ? bsum[t] : 0;
  s[t] = v;
  __syncthreads();
  for (int off = 1; off < 512; off <<= 1) {
    int tmp = (t >= off) ? s[t - off] : 0;
    __syncthreads();
    s[t] += tmp;
    __syncthreads();
  }
  if (t < NB) pb[t] = s[t] - v;  // exclusive prefix of block sums
}

__global__ void k_scan3(const int* __restrict__ deg, const int* __restrict__ pb,
                        int* __restrict__ offs, int* __restrict__ cursor) {
  int t = threadIdx.x, b = blockIdx.x;
  int i = b * 256 + t;
  if (i == 0) offs[0] = 0;
  if (i < NN) {
    int v = offs[i + 1] + pb[b];
    offs[i + 1] = v;          // final inclusive -> offs[i+1]
    cursor[i] = v - deg[i];   // exclusive start
  }
}

__global__ void k_scatter(const int* __restrict__ ei, int* __restrict__ cursor,
                          int* __restrict__ es) {
  int t = blockIdx.x * 256 + threadIdx.x;
  if (t >= ETOT) return;
  int s, dd;
  if (t < EE) {
    s = ei[t];
    dd = ei[(size_t)EE + t];
  } else {
    s = t - EE;
    dd = s;
  }
  int pos = atomicAdd(&cursor[dd], 1);
  es[pos] = s;
}

// one wave per destination node, single pass, NO cross-lane ops in the edge loop:
// lane owns channels (2*lane, 2*lane+1) of head h=lane>>4; it recomputes the edge
// weight for its own head (redundantly across the 16 lanes of that head), so the
// softmax denominator needs no reduction at all.
__global__ __launch_bounds__(256) void k_agg(const unsigned short* __restrict__ xwb,
                                             const float* __restrict__ a,
                                             const int* __restrict__ offs,
                                             const int* __restrict__ es,
                                             const float* __restrict__ bias,
                                             const float* __restrict__ gamma,
                                             const float* __restrict__ beta,
                                             float* __restrict__ out) {
  int lane = threadIdx.x & 63;
  int node = blockIdx.x * 4 + (threadIdx.x >> 6);
  int off0 = offs[node];
  int d = offs[node + 1] - off0;
  int h = lane >> 4;  // this lane's head
  int c = lane * 2;   // this lane's two channels
  float adh = a[(size_t)node * 8 + 4 + h];

  const unsigned* xp = (const unsigned*)xwb + lane;  // + src*64 dwords
  const int* ep = es + off0;
  float se = 0.f, accx = 0.f, accy = 0.f;

  int j = 0;
  for (; j + 2 <= d; j += 2) {  // two independent chains for ILP
    int2 sp = *((const int2*)(ep + j));
    float a0 = a[(size_t)sp.x * 8 + h];
    float a1 = a[(size_t)sp.y * 8 + h];
    unsigned u0 = xp[(size_t)sp.x * 64];
    unsigned u1 = xp[(size_t)sp.y * 64];
    float e0 = a0 + adh; e0 = (e0 > 0.f) ? e0 : 0.2f * e0; float w0 = __expf(e0);
    float e1 = a1 + adh; e1 = (e1 > 0.f) ? e1 : 0.2f * e1; float w1 = __expf(e1);
    se += w0 + w1;
    accx = fmaf(w0, __uint_as_float(u0 << 16), accx);
    accy = fmaf(w0, __uint_as_float(u0 & 0xffff0000u), accy);
    accx = fmaf(w1, __uint_as_float(u1 << 16), accx);
    accy = fmaf(w1, __uint_as_float(u1 & 0xffff0000u), accy);
  }
  if (j < d) {
    int s0 = ep[j];
    float a0 = a[(size_t)s0 * 8 + h];
    unsigned u0 = xp[(size_t)s0 * 64];
    float e0 = a0 + adh; e0 = (e0 > 0.f) ? e0 : 0.2f * e0; float w0 = __expf(e0);
    se += w0;
    accx = fmaf(w0, __uint_as_float(u0 << 16), accx);
    accy = fmaf(w0, __uint_as_float(u0 & 0xffff0000u), accy);
  }
  float rn = 1.f / (se + 1e-16f);

  // LayerNorm epilogue
  float vx = accx * rn + bias[c];
  float vy = accy * rn + bias[c + 1];
  float sum = vx + vy, sq = vx * vx + vy * vy;
#pragma unroll
  for (int o = 32; o; o >>= 1) {
    sum += __shfl_xor(sum, o);
    sq += __shfl_xor(sq, o);
  }
  float mean = sum * (1.f / 128.f);
  float var = sq * (1.f / 128.f) - mean * mean;
  float rs = rsqrtf(var + 1e-5f);
  float o0 = gamma[c] * (vx - mean) * rs + beta[c];
  float o1 = gamma[c + 1] * (vy - mean) * rs + beta[c + 1];
  float2 ov; ov.x = o0; ov.y = o1;
  *((float2*)(out + (size_t)node * 128 + c)) = ov;
}

extern "C" void kernel_launch(void* const* d_in, const int* in_sizes, int n_in,
                              void* d_out, int out_size, void* d_ws, size_t ws_size,
                              hipStream_t stream) {
  const float* x = (const float*)d_in[0];
  const int* ei = (const int*)d_in[1];  // harness passes integer inputs as int32
  // d_in[2] edge_weight: unused by reference
  const float* W = (const float*)d_in[3];
  const float* att_src = (const float*)d_in[4];
  const float* att_dst = (const float*)d_in[5];
  const float* bias = (const float*)d_in[6];
  const float* gamma = (const float*)d_in[7];
  const float* beta = (const float*)d_in[8];
  float* out = (float*)d_out;

  char* p = (char*)d_ws;
  auto alloc = [&](size_t bytes) -> char* {
    char* r = p;
    p += (bytes + 255) & ~(size_t)255;
    return r;
  };
  unsigned short* xwb = (unsigned short*)alloc((size_t)NN * 128 * 2);  // 25.6 MB bf16
  float* a = (float*)alloc((size_t)NN * 8 * 4);                        // 3.2 MB
  int* deg = (int*)alloc((size_t)NN * 4);
  int* offs = (int*)alloc((size_t)(NN + 1) * 4);
  int* cursor = (int*)alloc((size_t)NN * 4);
  int* bsum = (int*)alloc(512 * 4);
  int* pb = (int*)alloc(512 * 4);
  int* es = (int*)alloc((size_t)ETOT * 4);                             // 6.8 MB

  k_gemm<<<(NN + 63) / 64, 256, 0, stream>>>(x, W, att_src, att_dst, xwb, a);
  k_init<<<(NN + 255) / 256, 256, 0, stream>>>(deg);
  k_count<<<(EE + 255) / 256, 256, 0, stream>>>(ei, deg);
  k_scan1<<<NB, 256, 0, stream>>>(deg, offs, bsum);
  k_scan2<<<1, 512, 0, stream>>>(bsum, pb);
  k_scan3<<<NB, 256, 0, stream>>>(deg, pb, offs, cursor);
  k_scatter<<<(ETOT + 255) / 256, 256, 0, stream>>>(ei, cursor, es);
  k_agg<<<NN / 4, 256, 0, stream>>>(xwb, a, offs, es, bias, gamma, beta, out);
}

// Round 5
// 372.545 us; speedup vs baseline: 1.5987x; 1.4082x over previous
//
#include <hip/hip_runtime.h>
#include <math.h>

#define NN 100000
#define EE 1600000
#define ETOT (EE + NN)
#define NBUK 512
#define NPB 196        // nodes per bucket (512*196 >= NN)
#define CHUNK 3125     // 512*3125 == EE
#define CAP 6144       // LDS stage capacity per bucket (mean ~3332, +50 sigma)

__device__ __forceinline__ unsigned short f2bf(float f) {
  unsigned int u = __float_as_uint(f);
  u = u + 0x7fffu + ((u >> 16) & 1u);  // RNE
  return (unsigned short)(u >> 16);
}

// xw(bf16) = x @ W  (W staged bf16 in LDS); attention logits a[r][0..7] from the
// accumulator via cross-lane reduction (a_src h<4, a_dst h>=4).
__global__ __launch_bounds__(256) void k_gemm(const float* __restrict__ x,
                                              const float* __restrict__ W,
                                              const float* __restrict__ att_src,
                                              const float* __restrict__ att_dst,
                                              unsigned short* __restrict__ xwb,
                                              float* __restrict__ a) {
  __shared__ unsigned short Wl[16384];  // bf16 bits, [k][c]
  int tid = threadIdx.x;
  for (int i = tid; i < 16384; i += 256) Wl[i] = f2bf(W[i]);
  __syncthreads();

  int r0 = blockIdx.x * 64 + (tid >> 4) * 4;  // 4 rows per thread
  int c0 = (tid & 15) * 8;                    // 8 cols per thread (within one head)
  float acc[4][8];
#pragma unroll
  for (int i = 0; i < 4; i++)
#pragma unroll
    for (int j = 0; j < 8; j++) acc[i][j] = 0.f;

  for (int kc = 0; kc < 32; ++kc) {  // 4 k per chunk
    float xs[4][4];
#pragma unroll
    for (int i = 0; i < 4; i++) {
      int r = r0 + i;
      float4 v = (r < NN) ? ((const float4*)x)[(size_t)r * 32 + kc]
                          : make_float4(0.f, 0.f, 0.f, 0.f);
      xs[i][0] = v.x; xs[i][1] = v.y; xs[i][2] = v.z; xs[i][3] = v.w;
    }
#pragma unroll
    for (int q = 0; q < 4; q++) {
      int k = kc * 4 + q;
      uint4 wv = *((const uint4*)&Wl[k * 128 + c0]);
      float wf[8];
      wf[0] = __uint_as_float(wv.x << 16); wf[1] = __uint_as_float(wv.x & 0xffff0000u);
      wf[2] = __uint_as_float(wv.y << 16); wf[3] = __uint_as_float(wv.y & 0xffff0000u);
      wf[4] = __uint_as_float(wv.z << 16); wf[5] = __uint_as_float(wv.z & 0xffff0000u);
      wf[6] = __uint_as_float(wv.w << 16); wf[7] = __uint_as_float(wv.w & 0xffff0000u);
#pragma unroll
      for (int i = 0; i < 4; i++)
#pragma unroll
        for (int j = 0; j < 8; j++) acc[i][j] = fmaf(xs[i][q], wf[j], acc[i][j]);
    }
  }

  float as8[8], ad8[8];
#pragma unroll
  for (int j = 0; j < 8; j++) {
    as8[j] = att_src[c0 + j];
    ad8[j] = att_dst[c0 + j];
  }
#pragma unroll
  for (int i = 0; i < 4; i++) {
    int r = r0 + i;
    float ps = 0.f, pd = 0.f;
#pragma unroll
    for (int j = 0; j < 8; j++) {
      ps = fmaf(acc[i][j], as8[j], ps);
      pd = fmaf(acc[i][j], ad8[j], pd);
    }
    ps += __shfl_xor(ps, 1); ps += __shfl_xor(ps, 2);
    pd += __shfl_xor(pd, 1); pd += __shfl_xor(pd, 2);
    if (r < NN) {
      if ((tid & 3) == 0) {
        int h = (tid & 15) >> 2;
        a[(size_t)r * 8 + h] = ps;
        a[(size_t)r * 8 + 4 + h] = pd;
      }
      uint4 o;
      o.x = (unsigned)f2bf(acc[i][0]) | ((unsigned)f2bf(acc[i][1]) << 16);
      o.y = (unsigned)f2bf(acc[i][2]) | ((unsigned)f2bf(acc[i][3]) << 16);
      o.z = (unsigned)f2bf(acc[i][4]) | ((unsigned)f2bf(acc[i][5]) << 16);
      o.w = (unsigned)f2bf(acc[i][6]) | ((unsigned)f2bf(acc[i][7]) << 16);
      *((uint4*)(xwb + (size_t)r * 128 + c0)) = o;
    }
  }
}

// P1: per-(chunk, bucket) histogram. H[chunk][bucket], coalesced write.
__global__ __launch_bounds__(256) void k_p1(const int* __restrict__ ei,
                                            int* __restrict__ H) {
  __shared__ int h[NBUK];
  int j = blockIdx.x, t = threadIdx.x;
  for (int i = t; i < NBUK; i += 256) h[i] = 0;
  __syncthreads();
  int e0 = j * CHUNK;
  for (int e = e0 + t; e < e0 + CHUNK; e += 256) {
    int d = ei[(size_t)EE + e];
    atomicAdd(&h[d / NPB], 1);
  }
  __syncthreads();
  for (int i = t; i < NBUK; i += 256) H[j * NBUK + i] = h[i];
}

// S1: per-bucket exclusive scan over chunks. R[bucket][chunk] (coalesced write), T[bucket].
__global__ __launch_bounds__(512) void k_s1(const int* __restrict__ H,
                                            int* __restrict__ R, int* __restrict__ T) {
  __shared__ int s[512];
  int b = blockIdx.x, t = threadIdx.x;
  int v = H[t * NBUK + b];
  s[t] = v;
  __syncthreads();
  for (int off = 1; off < 512; off <<= 1) {
    int tmp = (t >= off) ? s[t - off] : 0;
    __syncthreads();
    s[t] += tmp;
    __syncthreads();
  }
  R[b * 512 + t] = s[t] - v;
  if (t == 511) T[b] = s[511];
}

// S2: bucket bases. BaseTmp = scan(T); Base = scan(T + nodecount(bucket)).
__global__ __launch_bounds__(512) void k_s2(const int* __restrict__ T,
                                            int* __restrict__ BaseTmp,
                                            int* __restrict__ Base) {
  __shared__ int s[512];
  __shared__ int s2[512];
  int t = threadIdx.x;
  int v = T[t];
  int ncnt = NN - t * NPB;
  ncnt = (ncnt < 0) ? 0 : ((ncnt > NPB) ? NPB : ncnt);
  int w = v + ncnt;
  s[t] = v; s2[t] = w;
  __syncthreads();
  for (int off = 1; off < 512; off <<= 1) {
    int ta = (t >= off) ? s[t - off] : 0;
    int tb = (t >= off) ? s2[t - off] : 0;
    __syncthreads();
    s[t] += ta; s2[t] += tb;
    __syncthreads();
  }
  BaseTmp[t] = s[t] - v;
  Base[t] = s2[t] - w;
}

// P3: deterministic partition by bucket; LDS cursors only. tmp word = (local_id<<17)|src.
__global__ __launch_bounds__(256) void k_p3(const int* __restrict__ ei,
                                            const int* __restrict__ R,
                                            const int* __restrict__ BaseTmp,
                                            int* __restrict__ tmpb) {
  __shared__ int cur[NBUK];
  int j = blockIdx.x, t = threadIdx.x;
  for (int b = t; b < NBUK; b += 256) cur[b] = BaseTmp[b] + R[b * 512 + j];
  __syncthreads();
  int e0 = j * CHUNK;
  for (int e = e0 + t; e < e0 + CHUNK; e += 256) {
    int s = ei[e];
    int d = ei[(size_t)EE + e];
    int b = d / NPB;
    int li = d - b * NPB;
    int pos = atomicAdd(&cur[b], 1);
    tmpb[pos] = (li << 17) | s;
  }
}

// P4: one block per bucket: per-node count/scan/scatter in LDS; coalesced es + offs.
__global__ __launch_bounds__(256) void k_p4(const int* __restrict__ tmpb,
                                            const int* __restrict__ T,
                                            const int* __restrict__ BaseTmp,
                                            const int* __restrict__ Base,
                                            int* __restrict__ es, int* __restrict__ offs) {
  __shared__ int cnt[256];
  __shared__ int cur[NPB];
  __shared__ int stage[CAP];
  int b = blockIdx.x, t = threadIdx.x;
  if (b == 0 && t == 0) offs[NN] = ETOT;
  int n0 = b * NPB;
  int nloc = NN - n0;
  if (nloc <= 0) return;
  if (nloc > NPB) nloc = NPB;
  int total = T[b];
  int bt = BaseTmp[b], bs = Base[b];
  cnt[t] = (t < nloc) ? 1 : 0;  // self-loop pre-counted
  __syncthreads();
  for (int e = t; e < total; e += 256) {
    int u = tmpb[bt + e];
    atomicAdd(&cnt[u >> 17], 1);
  }
  __syncthreads();
  int v = cnt[t];
  __syncthreads();
  for (int off = 1; off < 256; off <<= 1) {
    int tmp = (t >= off) ? cnt[t - off] : 0;
    __syncthreads();
    cnt[t] += tmp;
    __syncthreads();
  }
  int excl = cnt[t] - v;
  if (t < nloc) {
    offs[n0 + t] = bs + excl;
    if (excl < CAP) stage[excl] = n0 + t;  // self-loop src first
    cur[t] = excl + 1;
  }
  __syncthreads();
  for (int e = t; e < total; e += 256) {
    int u = tmpb[bt + e];
    int li = u >> 17;
    int pos = atomicAdd(&cur[li], 1);
    if (pos < CAP) stage[pos] = u & 0x1FFFF;
  }
  __syncthreads();
  int btot = total + nloc;
  if (btot > CAP) btot = CAP;
  for (int i = t; i < btot; i += 256) es[bs + i] = stage[i];
}

// one wave per destination node, single pass, no cross-lane ops in the edge loop.
__global__ __launch_bounds__(256) void k_agg(const unsigned short* __restrict__ xwb,
                                             const float* __restrict__ a,
                                             const int* __restrict__ offs,
                                             const int* __restrict__ es,
                                             const float* __restrict__ bias,
                                             const float* __restrict__ gamma,
                                             const float* __restrict__ beta,
                                             float* __restrict__ out) {
  int lane = threadIdx.x & 63;
  int node = blockIdx.x * 4 + (threadIdx.x >> 6);
  int off0 = offs[node];
  int d = offs[node + 1] - off0;
  int h = lane >> 4;
  int c = lane * 2;
  float adh = a[(size_t)node * 8 + 4 + h];

  const unsigned* xp = (const unsigned*)xwb + lane;
  const int* ep = es + off0;
  float se = 0.f, accx = 0.f, accy = 0.f;

  int j = 0;
  for (; j + 2 <= d; j += 2) {
    int2 sp = *((const int2*)(ep + j));
    float a0 = a[(size_t)sp.x * 8 + h];
    float a1 = a[(size_t)sp.y * 8 + h];
    unsigned u0 = xp[(size_t)sp.x * 64];
    unsigned u1 = xp[(size_t)sp.y * 64];
    float e0 = a0 + adh; e0 = (e0 > 0.f) ? e0 : 0.2f * e0; float w0 = __expf(e0);
    float e1 = a1 + adh; e1 = (e1 > 0.f) ? e1 : 0.2f * e1; float w1 = __expf(e1);
    se += w0 + w1;
    accx = fmaf(w0, __uint_as_float(u0 << 16), accx);
    accy = fmaf(w0, __uint_as_float(u0 & 0xffff0000u), accy);
    accx = fmaf(w1, __uint_as_float(u1 << 16), accx);
    accy = fmaf(w1, __uint_as_float(u1 & 0xffff0000u), accy);
  }
  if (j < d) {
    int s0 = ep[j];
    float a0 = a[(size_t)s0 * 8 + h];
    unsigned u0 = xp[(size_t)s0 * 64];
    float e0 = a0 + adh; e0 = (e0 > 0.f) ? e0 : 0.2f * e0; float w0 = __expf(e0);
    se += w0;
    accx = fmaf(w0, __uint_as_float(u0 << 16), accx);
    accy = fmaf(w0, __uint_as_float(u0 & 0xffff0000u), accy);
  }
  float rn = 1.f / (se + 1e-16f);

  float vx = accx * rn + bias[c];
  float vy = accy * rn + bias[c + 1];
  float sum = vx + vy, sq = vx * vx + vy * vy;
#pragma unroll
  for (int o = 32; o; o >>= 1) {
    sum += __shfl_xor(sum, o);
    sq += __shfl_xor(sq, o);
  }
  float mean = sum * (1.f / 128.f);
  float var = sq * (1.f / 128.f) - mean * mean;
  float rs = rsqrtf(var + 1e-5f);
  float o0 = gamma[c] * (vx - mean) * rs + beta[c];
  float o1 = gamma[c + 1] * (vy - mean) * rs + beta[c + 1];
  float2 ov; ov.x = o0; ov.y = o1;
  *((float2*)(out + (size_t)node * 128 + c)) = ov;
}

extern "C" void kernel_launch(void* const* d_in, const int* in_sizes, int n_in,
                              void* d_out, int out_size, void* d_ws, size_t ws_size,
                              hipStream_t stream) {
  const float* x = (const float*)d_in[0];
  const int* ei = (const int*)d_in[1];  // int32 per harness contract
  const float* W = (const float*)d_in[3];
  const float* att_src = (const float*)d_in[4];
  const float* att_dst = (const float*)d_in[5];
  const float* bias = (const float*)d_in[6];
  const float* gamma = (const float*)d_in[7];
  const float* beta = (const float*)d_in[8];
  float* out = (float*)d_out;

  char* p = (char*)d_ws;
  auto alloc = [&](size_t bytes) -> char* {
    char* r = p;
    p += (bytes + 255) & ~(size_t)255;
    return r;
  };
  unsigned short* xwb = (unsigned short*)alloc((size_t)NN * 128 * 2);  // 25.6 MB
  float* a = (float*)alloc((size_t)NN * 8 * 4);                        // 3.2 MB
  int* es = (int*)alloc((size_t)ETOT * 4);                             // 6.8 MB
  int* offs = (int*)alloc((size_t)(NN + 1) * 4);
  int* tmpb = (int*)alloc((size_t)EE * 4);                             // 6.4 MB
  int* H = (int*)alloc((size_t)512 * NBUK * 4);                        // 1 MB
  int* R = (int*)alloc((size_t)NBUK * 512 * 4);                        // 1 MB
  int* T = (int*)alloc((size_t)NBUK * 4);
  int* BaseTmp = (int*)alloc((size_t)(NBUK + 1) * 4);
  int* Base = (int*)alloc((size_t)(NBUK + 1) * 4);

  k_gemm<<<(NN + 63) / 64, 256, 0, stream>>>(x, W, att_src, att_dst, xwb, a);
  k_p1<<<512, 256, 0, stream>>>(ei, H);
  k_s1<<<NBUK, 512, 0, stream>>>(H, R, T);
  k_s2<<<1, 512, 0, stream>>>(T, BaseTmp, Base);
  k_p3<<<512, 256, 0, stream>>>(ei, R, BaseTmp, tmpb);
  k_p4<<<NBUK, 256, 0, stream>>>(tmpb, T, BaseTmp, Base, es, offs);
  k_agg<<<NN / 4, 256, 0, stream>>>(xwb, a, offs, es, bias, gamma, beta, out);
}

// Round 6
// 372.301 us; speedup vs baseline: 1.5997x; 1.0007x over previous
//
#include <hip/hip_runtime.h>
#include <math.h>

#define NN 100000
#define EE 1600000
#define ETOT (EE + NN)
#define NBUK 512
#define NPB 196        // nodes per bucket (512*196 >= NN)
#define CHUNK 3125     // 512*3125 == EE
#define CAP 6144       // LDS stage capacity per bucket (mean ~3332, +50 sigma)

__device__ __forceinline__ unsigned short f2bf(float f) {
  unsigned int u = __float_as_uint(f);
  u = u + 0x7fffu + ((u >> 16) & 1u);  // RNE
  return (unsigned short)(u >> 16);
}

__device__ __forceinline__ float lrelu_exp(float e) {
  e = (e > 0.f) ? e : 0.2f * e;
  return __expf(e);
}

// xw(bf16) = x @ W  (W staged bf16 in LDS); attention logits a[r][0..7] from the
// accumulator via cross-lane reduction (a_src h<4, a_dst h>=4).
__global__ __launch_bounds__(256) void k_gemm(const float* __restrict__ x,
                                              const float* __restrict__ W,
                                              const float* __restrict__ att_src,
                                              const float* __restrict__ att_dst,
                                              unsigned short* __restrict__ xwb,
                                              float* __restrict__ a) {
  __shared__ unsigned short Wl[16384];  // bf16 bits, [k][c]
  int tid = threadIdx.x;
  for (int i = tid; i < 16384; i += 256) Wl[i] = f2bf(W[i]);
  __syncthreads();

  int r0 = blockIdx.x * 64 + (tid >> 4) * 4;  // 4 rows per thread
  int c0 = (tid & 15) * 8;                    // 8 cols per thread (within one head)
  float acc[4][8];
#pragma unroll
  for (int i = 0; i < 4; i++)
#pragma unroll
    for (int j = 0; j < 8; j++) acc[i][j] = 0.f;

  for (int kc = 0; kc < 32; ++kc) {  // 4 k per chunk
    float xs[4][4];
#pragma unroll
    for (int i = 0; i < 4; i++) {
      int r = r0 + i;
      float4 v = (r < NN) ? ((const float4*)x)[(size_t)r * 32 + kc]
                          : make_float4(0.f, 0.f, 0.f, 0.f);
      xs[i][0] = v.x; xs[i][1] = v.y; xs[i][2] = v.z; xs[i][3] = v.w;
    }
#pragma unroll
    for (int q = 0; q < 4; q++) {
      int k = kc * 4 + q;
      uint4 wv = *((const uint4*)&Wl[k * 128 + c0]);
      float wf[8];
      wf[0] = __uint_as_float(wv.x << 16); wf[1] = __uint_as_float(wv.x & 0xffff0000u);
      wf[2] = __uint_as_float(wv.y << 16); wf[3] = __uint_as_float(wv.y & 0xffff0000u);
      wf[4] = __uint_as_float(wv.z << 16); wf[5] = __uint_as_float(wv.z & 0xffff0000u);
      wf[6] = __uint_as_float(wv.w << 16); wf[7] = __uint_as_float(wv.w & 0xffff0000u);
#pragma unroll
      for (int i = 0; i < 4; i++)
#pragma unroll
        for (int j = 0; j < 8; j++) acc[i][j] = fmaf(xs[i][q], wf[j], acc[i][j]);
    }
  }

  float as8[8], ad8[8];
#pragma unroll
  for (int j = 0; j < 8; j++) {
    as8[j] = att_src[c0 + j];
    ad8[j] = att_dst[c0 + j];
  }
#pragma unroll
  for (int i = 0; i < 4; i++) {
    int r = r0 + i;
    float ps = 0.f, pd = 0.f;
#pragma unroll
    for (int j = 0; j < 8; j++) {
      ps = fmaf(acc[i][j], as8[j], ps);
      pd = fmaf(acc[i][j], ad8[j], pd);
    }
    ps += __shfl_xor(ps, 1); ps += __shfl_xor(ps, 2);
    pd += __shfl_xor(pd, 1); pd += __shfl_xor(pd, 2);
    if (r < NN) {
      if ((tid & 3) == 0) {
        int h = (tid & 15) >> 2;
        a[(size_t)r * 8 + h] = ps;
        a[(size_t)r * 8 + 4 + h] = pd;
      }
      uint4 o;
      o.x = (unsigned)f2bf(acc[i][0]) | ((unsigned)f2bf(acc[i][1]) << 16);
      o.y = (unsigned)f2bf(acc[i][2]) | ((unsigned)f2bf(acc[i][3]) << 16);
      o.z = (unsigned)f2bf(acc[i][4]) | ((unsigned)f2bf(acc[i][5]) << 16);
      o.w = (unsigned)f2bf(acc[i][6]) | ((unsigned)f2bf(acc[i][7]) << 16);
      *((uint4*)(xwb + (size_t)r * 128 + c0)) = o;
    }
  }
}

// P1: per-(chunk, bucket) histogram. H[chunk][bucket], coalesced write.
__global__ __launch_bounds__(256) void k_p1(const int* __restrict__ ei,
                                            int* __restrict__ H) {
  __shared__ int h[NBUK];
  int j = blockIdx.x, t = threadIdx.x;
  for (int i = t; i < NBUK; i += 256) h[i] = 0;
  __syncthreads();
  int e0 = j * CHUNK;
  for (int e = e0 + t; e < e0 + CHUNK; e += 256) {
    int d = ei[(size_t)EE + e];
    atomicAdd(&h[d / NPB], 1);
  }
  __syncthreads();
  for (int i = t; i < NBUK; i += 256) H[j * NBUK + i] = h[i];
}

// S1: per-bucket exclusive scan over chunks. R[bucket][chunk], totals T[bucket].
__global__ __launch_bounds__(512) void k_s1(const int* __restrict__ H,
                                            int* __restrict__ R, int* __restrict__ T) {
  __shared__ int s[512];
  int b = blockIdx.x, t = threadIdx.x;
  int v = H[t * NBUK + b];
  s[t] = v;
  __syncthreads();
  for (int off = 1; off < 512; off <<= 1) {
    int tmp = (t >= off) ? s[t - off] : 0;
    __syncthreads();
    s[t] += tmp;
    __syncthreads();
  }
  R[b * 512 + t] = s[t] - v;
  if (t == 511) T[b] = s[511];
}

// S2: bucket bases. BaseTmp = scan(T); Base = scan(T + nodecount(bucket)).
__global__ __launch_bounds__(512) void k_s2(const int* __restrict__ T,
                                            int* __restrict__ BaseTmp,
                                            int* __restrict__ Base) {
  __shared__ int s[512];
  __shared__ int s2[512];
  int t = threadIdx.x;
  int v = T[t];
  int ncnt = NN - t * NPB;
  ncnt = (ncnt < 0) ? 0 : ((ncnt > NPB) ? NPB : ncnt);
  int w = v + ncnt;
  s[t] = v; s2[t] = w;
  __syncthreads();
  for (int off = 1; off < 512; off <<= 1) {
    int ta = (t >= off) ? s[t - off] : 0;
    int tb = (t >= off) ? s2[t - off] : 0;
    __syncthreads();
    s[t] += ta; s2[t] += tb;
    __syncthreads();
  }
  BaseTmp[t] = s[t] - v;
  Base[t] = s2[t] - w;
}

// P3: deterministic partition by bucket; LDS cursors only. tmp word = (local_id<<17)|src.
__global__ __launch_bounds__(256) void k_p3(const int* __restrict__ ei,
                                            const int* __restrict__ R,
                                            const int* __restrict__ BaseTmp,
                                            int* __restrict__ tmpb) {
  __shared__ int cur[NBUK];
  int j = blockIdx.x, t = threadIdx.x;
  for (int b = t; b < NBUK; b += 256) cur[b] = BaseTmp[b] + R[b * 512 + j];
  __syncthreads();
  int e0 = j * CHUNK;
  for (int e = e0 + t; e < e0 + CHUNK; e += 256) {
    int s = ei[e];
    int d = ei[(size_t)EE + e];
    int b = d / NPB;
    int li = d - b * NPB;
    int pos = atomicAdd(&cur[b], 1);
    tmpb[pos] = (li << 17) | s;
  }
}

// P4: one block per bucket: per-node count/scan/scatter in LDS; coalesced es + offs.
// Also computes per-edge softmax numerators ew[slot][4] and per-node reciprocal
// denominators na[node][4] (LDS float atomics) — k_agg becomes pure gather+FMA.
__global__ __launch_bounds__(256) void k_p4(const int* __restrict__ tmpb,
                                            const int* __restrict__ T,
                                            const int* __restrict__ BaseTmp,
                                            const int* __restrict__ Base,
                                            const float* __restrict__ a,
                                            int* __restrict__ es, int* __restrict__ offs,
                                            float* __restrict__ ew,
                                            float* __restrict__ na) {
  __shared__ int cnt[256];
  __shared__ int cur[NPB];
  __shared__ int stage[CAP];
  __shared__ float ssum[NPB * 4];
  int b = blockIdx.x, t = threadIdx.x;
  if (b == 0 && t == 0) offs[NN] = ETOT;
  int n0 = b * NPB;
  int nloc = NN - n0;
  if (nloc <= 0) return;
  if (nloc > NPB) nloc = NPB;
  int total = T[b];
  int bt = BaseTmp[b], bs = Base[b];
  cnt[t] = (t < nloc) ? 1 : 0;  // self-loop pre-counted
  for (int i = t; i < NPB * 4; i += 256) ssum[i] = 0.f;
  __syncthreads();
  for (int e = t; e < total; e += 256) {
    int u = tmpb[bt + e];
    atomicAdd(&cnt[u >> 17], 1);
  }
  __syncthreads();
  int v = cnt[t];
  __syncthreads();
  for (int off = 1; off < 256; off <<= 1) {
    int tmp = (t >= off) ? cnt[t - off] : 0;
    __syncthreads();
    cnt[t] += tmp;
    __syncthreads();
  }
  int excl = cnt[t] - v;
  if (t < nloc) {
    int node = n0 + t;
    offs[node] = bs + excl;
    cur[t] = excl + 1;
    if (excl < CAP) {
      stage[excl] = node;  // self-loop src first
      float4 asv = *((const float4*)(a + (size_t)node * 8));
      float4 adv = *((const float4*)(a + (size_t)node * 8 + 4));
      float4 w4;
      w4.x = lrelu_exp(asv.x + adv.x); w4.y = lrelu_exp(asv.y + adv.y);
      w4.z = lrelu_exp(asv.z + adv.z); w4.w = lrelu_exp(asv.w + adv.w);
      *((float4*)(ew + (size_t)(bs + excl) * 4)) = w4;
      atomicAdd(&ssum[t * 4 + 0], w4.x); atomicAdd(&ssum[t * 4 + 1], w4.y);
      atomicAdd(&ssum[t * 4 + 2], w4.z); atomicAdd(&ssum[t * 4 + 3], w4.w);
    }
  }
  __syncthreads();
  for (int e = t; e < total; e += 256) {
    int u = tmpb[bt + e];
    int li = u >> 17;
    int src = u & 0x1FFFF;
    int pos = atomicAdd(&cur[li], 1);
    if (pos < CAP) {
      stage[pos] = src;
      float4 asv = *((const float4*)(a + (size_t)src * 8));
      float4 adv = *((const float4*)(a + (size_t)(n0 + li) * 8 + 4));
      float4 w4;
      w4.x = lrelu_exp(asv.x + adv.x); w4.y = lrelu_exp(asv.y + adv.y);
      w4.z = lrelu_exp(asv.z + adv.z); w4.w = lrelu_exp(asv.w + adv.w);
      *((float4*)(ew + (size_t)(bs + pos) * 4)) = w4;
      atomicAdd(&ssum[li * 4 + 0], w4.x); atomicAdd(&ssum[li * 4 + 1], w4.y);
      atomicAdd(&ssum[li * 4 + 2], w4.z); atomicAdd(&ssum[li * 4 + 3], w4.w);
    }
  }
  __syncthreads();
  int btot = total + nloc;
  if (btot > CAP) btot = CAP;
  for (int i = t; i < btot; i += 256) es[bs + i] = stage[i];
  for (int i = t; i < nloc * 4; i += 256)
    na[(size_t)n0 * 4 + i] = 1.f / (ssum[i] + 1e-16f);
}

// one wave per destination node: pure gather+FMA (weights precomputed in P4).
__global__ __launch_bounds__(256) void k_agg(const unsigned short* __restrict__ xwb,
                                             const float* __restrict__ ew,
                                             const float* __restrict__ na,
                                             const int* __restrict__ offs,
                                             const int* __restrict__ es,
                                             const float* __restrict__ bias,
                                             const float* __restrict__ gamma,
                                             const float* __restrict__ beta,
                                             float* __restrict__ out) {
  int lane = threadIdx.x & 63;
  int node = blockIdx.x * 4 + (threadIdx.x >> 6);
  int off0 = offs[node];
  int d = offs[node + 1] - off0;
  int h = lane >> 4;
  int c = lane * 2;
  float rn = na[(size_t)node * 4 + h];

  const unsigned* xp = (const unsigned*)xwb + lane;
  const int* ep = es + off0;
  const float* wp = ew + (size_t)off0 * 4 + h;
  float ax0 = 0.f, ay0 = 0.f, ax1 = 0.f, ay1 = 0.f;

  int j = 0;
  for (; j + 4 <= d; j += 4) {
    int4 sp = *((const int4*)(ep + j));
    float w0 = wp[4 * j];
    float w1 = wp[4 * j + 4];
    float w2 = wp[4 * j + 8];
    float w3 = wp[4 * j + 12];
    unsigned u0 = xp[(unsigned)sp.x * 64u];
    unsigned u1 = xp[(unsigned)sp.y * 64u];
    unsigned u2 = xp[(unsigned)sp.z * 64u];
    unsigned u3 = xp[(unsigned)sp.w * 64u];
    ax0 = fmaf(w0, __uint_as_float(u0 << 16), ax0);
    ay0 = fmaf(w0, __uint_as_float(u0 & 0xffff0000u), ay0);
    ax1 = fmaf(w1, __uint_as_float(u1 << 16), ax1);
    ay1 = fmaf(w1, __uint_as_float(u1 & 0xffff0000u), ay1);
    ax0 = fmaf(w2, __uint_as_float(u2 << 16), ax0);
    ay0 = fmaf(w2, __uint_as_float(u2 & 0xffff0000u), ay0);
    ax1 = fmaf(w3, __uint_as_float(u3 << 16), ax1);
    ay1 = fmaf(w3, __uint_as_float(u3 & 0xffff0000u), ay1);
  }
  for (; j < d; ++j) {
    int s0 = ep[j];
    float w0 = wp[4 * j];
    unsigned u0 = xp[(unsigned)s0 * 64u];
    ax0 = fmaf(w0, __uint_as_float(u0 << 16), ax0);
    ay0 = fmaf(w0, __uint_as_float(u0 & 0xffff0000u), ay0);
  }
  float accx = ax0 + ax1, accy = ay0 + ay1;

  float vx = accx * rn + bias[c];
  float vy = accy * rn + bias[c + 1];
  float sum = vx + vy, sq = vx * vx + vy * vy;
#pragma unroll
  for (int o = 32; o; o >>= 1) {
    sum += __shfl_xor(sum, o);
    sq += __shfl_xor(sq, o);
  }
  float mean = sum * (1.f / 128.f);
  float var = sq * (1.f / 128.f) - mean * mean;
  float rs = rsqrtf(var + 1e-5f);
  float o0 = gamma[c] * (vx - mean) * rs + beta[c];
  float o1 = gamma[c + 1] * (vy - mean) * rs + beta[c + 1];
  float2 ov; ov.x = o0; ov.y = o1;
  *((float2*)(out + (size_t)node * 128 + c)) = ov;
}

extern "C" void kernel_launch(void* const* d_in, const int* in_sizes, int n_in,
                              void* d_out, int out_size, void* d_ws, size_t ws_size,
                              hipStream_t stream) {
  const float* x = (const float*)d_in[0];
  const int* ei = (const int*)d_in[1];  // int32 per harness contract
  const float* W = (const float*)d_in[3];
  const float* att_src = (const float*)d_in[4];
  const float* att_dst = (const float*)d_in[5];
  const float* bias = (const float*)d_in[6];
  const float* gamma = (const float*)d_in[7];
  const float* beta = (const float*)d_in[8];
  float* out = (float*)d_out;

  char* p = (char*)d_ws;
  auto alloc = [&](size_t bytes) -> char* {
    char* r = p;
    p += (bytes + 255) & ~(size_t)255;
    return r;
  };
  unsigned short* xwb = (unsigned short*)alloc((size_t)NN * 128 * 2);  // 25.6 MB
  float* a = (float*)alloc((size_t)NN * 8 * 4);                        // 3.2 MB
  int* es = (int*)alloc((size_t)ETOT * 4);                             // 6.8 MB
  int* offs = (int*)alloc((size_t)(NN + 1) * 4);
  float* ew = (float*)alloc((size_t)ETOT * 4 * 4);                     // 27.2 MB
  float* na = (float*)alloc((size_t)NN * 4 * 4);                       // 1.6 MB
  int* tmpb = (int*)alloc((size_t)EE * 4);                             // 6.4 MB
  int* H = (int*)alloc((size_t)512 * NBUK * 4);                        // 1 MB
  int* R = (int*)alloc((size_t)NBUK * 512 * 4);                        // 1 MB
  int* T = (int*)alloc((size_t)NBUK * 4);
  int* BaseTmp = (int*)alloc((size_t)(NBUK + 1) * 4);
  int* Base = (int*)alloc((size_t)(NBUK + 1) * 4);

  k_gemm<<<(NN + 63) / 64, 256, 0, stream>>>(x, W, att_src, att_dst, xwb, a);
  k_p1<<<512, 256, 0, stream>>>(ei, H);
  k_s1<<<NBUK, 512, 0, stream>>>(H, R, T);
  k_s2<<<1, 512, 0, stream>>>(T, BaseTmp, Base);
  k_p3<<<512, 256, 0, stream>>>(ei, R, BaseTmp, tmpb);
  k_p4<<<NBUK, 256, 0, stream>>>(tmpb, T, BaseTmp, Base, a, es, offs, ew, na);
  k_agg<<<NN / 4, 256, 0, stream>>>(xwb, ew, na, offs, es, bias, gamma, beta, out);
}

// Round 7
// 305.281 us; speedup vs baseline: 1.9509x; 1.2195x over previous
//
#include <hip/hip_runtime.h>
#include <math.h>

#define NN 100000
#define EE 1600000
#define ETOT (EE + NN)
#define NBUK 512
#define NPB 196        // nodes per bucket (512*196 >= NN)
#define CHUNK 3125     // 512*3125 == EE
#define CAP 6144       // LDS stage capacity per bucket (mean ~3332, +50 sigma)

typedef __attribute__((ext_vector_type(8))) short bf16x8;
typedef __attribute__((ext_vector_type(4))) float f32x4;

__device__ __forceinline__ unsigned short f2bf(float f) {
  unsigned int u = __float_as_uint(f);
  u = u + 0x7fffu + ((u >> 16) & 1u);  // RNE
  return (unsigned short)(u >> 16);
}

__device__ __forceinline__ float lrelu_exp(float e) {
  e = (e > 0.f) ? e : 0.2f * e;
  return __expf(e);
}

// MFMA bf16 GEMM: xwb = bf16(x @ W). Block = 64 rows (4 waves x 16), N=128 full.
// A-frag: A[m=lane&15][k=quad*8+j]; B-frag: B[k=quad*8+j][n=lane&15];
// C/D: row=quad*4+reg, col=lane&15  (HW-verified layouts).
__global__ __launch_bounds__(256) void k_gemm(const float* __restrict__ x,
                                              const float* __restrict__ W,
                                              unsigned short* __restrict__ xwb) {
  __shared__ __align__(16) unsigned short lds[17408];  // Wt[128][136] bf16; reused as stage[64][128]
  int tid = threadIdx.x;
  // stage W^T (bf16) : Wt[n][k], padded row stride 136 to break bank conflicts
  for (int i = tid; i < 16384; i += 256) {
    int k = i >> 7, n = i & 127;
    lds[n * 136 + k] = f2bf(W[i]);
  }
  __syncthreads();

  int wv = tid >> 6, lane = tid & 63;
  int m = lane & 15, q = lane >> 4;
  int r = blockIdx.x * 64 + wv * 16 + m;  // this lane's A row
  bool rok = (r < NN);

  // A fragments for all 4 k-tiles: af[kt][j] = bf16(x[r][kt*32 + q*8 + j])
  bf16x8 af[4];
#pragma unroll
  for (int kt = 0; kt < 4; kt++) {
    float4 v0 = make_float4(0.f, 0.f, 0.f, 0.f), v1 = v0;
    if (rok) {
      v0 = ((const float4*)x)[(size_t)r * 32 + kt * 8 + q * 2];
      v1 = ((const float4*)x)[(size_t)r * 32 + kt * 8 + q * 2 + 1];
    }
    af[kt][0] = (short)f2bf(v0.x); af[kt][1] = (short)f2bf(v0.y);
    af[kt][2] = (short)f2bf(v0.z); af[kt][3] = (short)f2bf(v0.w);
    af[kt][4] = (short)f2bf(v1.x); af[kt][5] = (short)f2bf(v1.y);
    af[kt][6] = (short)f2bf(v1.z); af[kt][7] = (short)f2bf(v1.w);
  }

  f32x4 acc[8];
#pragma unroll
  for (int nt = 0; nt < 8; nt++) acc[nt] = (f32x4){0.f, 0.f, 0.f, 0.f};

#pragma unroll
  for (int nt = 0; nt < 8; nt++) {
#pragma unroll
    for (int kt = 0; kt < 4; kt++) {
      bf16x8 bf = *((const bf16x8*)&lds[(nt * 16 + m) * 136 + kt * 32 + q * 8]);
      acc[nt] = __builtin_amdgcn_mfma_f32_16x16x32_bf16(af[kt], bf, acc[nt], 0, 0, 0);
    }
  }

  __syncthreads();  // all waves done reading Wt; reuse LDS as output stage
#pragma unroll
  for (int nt = 0; nt < 8; nt++)
#pragma unroll
    for (int rg = 0; rg < 4; rg++)
      lds[(wv * 16 + q * 4 + rg) * 128 + nt * 16 + m] = f2bf(acc[nt][rg]);
  __syncthreads();

  size_t base = (size_t)blockIdx.x * 16384;  // bytes; block tile is contiguous
  const size_t lim = (size_t)NN * 256;
  for (int i = tid; i < 1024; i += 256) {
    size_t off = base + (size_t)i * 16;
    if (off < lim) *((uint4*)((char*)xwb + off)) = ((const uint4*)lds)[i];
  }
}

// logits from bf16 xw: 4 lanes per node, one head each (32 contiguous channels).
__global__ __launch_bounds__(256) void k_logit(const unsigned short* __restrict__ xwb,
                                               const float* __restrict__ att_src,
                                               const float* __restrict__ att_dst,
                                               float* __restrict__ a) {
  __shared__ float att[256];
  int tid = threadIdx.x;
  if (tid < 128) att[tid] = att_src[tid];
  else if (tid < 256) att[tid] = att_dst[tid - 128];
  __syncthreads();
  int g = blockIdx.x * 256 + tid;
  int node = g >> 2, h = g & 3;
  if (node >= NN) return;
  const uint4* row = (const uint4*)(xwb + (size_t)node * 128) + h * 4;
  float ss = 0.f, sd = 0.f;
#pragma unroll
  for (int cq = 0; cq < 4; cq++) {
    uint4 u = row[cq];
    int cb = h * 32 + cq * 8;
    float f0 = __uint_as_float(u.x << 16), f1 = __uint_as_float(u.x & 0xffff0000u);
    float f2 = __uint_as_float(u.y << 16), f3 = __uint_as_float(u.y & 0xffff0000u);
    float f4 = __uint_as_float(u.z << 16), f5 = __uint_as_float(u.z & 0xffff0000u);
    float f6 = __uint_as_float(u.w << 16), f7 = __uint_as_float(u.w & 0xffff0000u);
    ss += f0 * att[cb] + f1 * att[cb + 1] + f2 * att[cb + 2] + f3 * att[cb + 3] +
          f4 * att[cb + 4] + f5 * att[cb + 5] + f6 * att[cb + 6] + f7 * att[cb + 7];
    sd += f0 * att[128 + cb] + f1 * att[128 + cb + 1] + f2 * att[128 + cb + 2] +
          f3 * att[128 + cb + 3] + f4 * att[128 + cb + 4] + f5 * att[128 + cb + 5] +
          f6 * att[128 + cb + 6] + f7 * att[128 + cb + 7];
  }
  a[(size_t)node * 8 + h] = ss;
  a[(size_t)node * 8 + 4 + h] = sd;
}

// P1: per-(chunk, bucket) histogram. H[chunk][bucket], coalesced write.
__global__ __launch_bounds__(256) void k_p1(const int* __restrict__ ei,
                                            int* __restrict__ H) {
  __shared__ int h[NBUK];
  int j = blockIdx.x, t = threadIdx.x;
  for (int i = t; i < NBUK; i += 256) h[i] = 0;
  __syncthreads();
  int e0 = j * CHUNK;
  for (int e = e0 + t; e < e0 + CHUNK; e += 256) {
    int d = ei[(size_t)EE + e];
    atomicAdd(&h[d / NPB], 1);
  }
  __syncthreads();
  for (int i = t; i < NBUK; i += 256) H[j * NBUK + i] = h[i];
}

// S1: per-bucket exclusive scan over chunks. R[bucket][chunk], totals T[bucket].
__global__ __launch_bounds__(512) void k_s1(const int* __restrict__ H,
                                            int* __restrict__ R, int* __restrict__ T) {
  __shared__ int s[512];
  int b = blockIdx.x, t = threadIdx.x;
  int v = H[t * NBUK + b];
  s[t] = v;
  __syncthreads();
  for (int off = 1; off < 512; off <<= 1) {
    int tmp = (t >= off) ? s[t - off] : 0;
    __syncthreads();
    s[t] += tmp;
    __syncthreads();
  }
  R[b * 512 + t] = s[t] - v;
  if (t == 511) T[b] = s[511];
}

// S2: bucket bases. BaseTmp = scan(T); Base = scan(T + nodecount(bucket)).
__global__ __launch_bounds__(512) void k_s2(const int* __restrict__ T,
                                            int* __restrict__ BaseTmp,
                                            int* __restrict__ Base) {
  __shared__ int s[512];
  __shared__ int s2[512];
  int t = threadIdx.x;
  int v = T[t];
  int ncnt = NN - t * NPB;
  ncnt = (ncnt < 0) ? 0 : ((ncnt > NPB) ? NPB : ncnt);
  int w = v + ncnt;
  s[t] = v; s2[t] = w;
  __syncthreads();
  for (int off = 1; off < 512; off <<= 1) {
    int ta = (t >= off) ? s[t - off] : 0;
    int tb = (t >= off) ? s2[t - off] : 0;
    __syncthreads();
    s[t] += ta; s2[t] += tb;
    __syncthreads();
  }
  BaseTmp[t] = s[t] - v;
  Base[t] = s2[t] - w;
}

// P3: deterministic partition by bucket; LDS cursors only. tmp word = (local_id<<17)|src.
__global__ __launch_bounds__(256) void k_p3(const int* __restrict__ ei,
                                            const int* __restrict__ R,
                                            const int* __restrict__ BaseTmp,
                                            int* __restrict__ tmpb) {
  __shared__ int cur[NBUK];
  int j = blockIdx.x, t = threadIdx.x;
  for (int b = t; b < NBUK; b += 256) cur[b] = BaseTmp[b] + R[b * 512 + j];
  __syncthreads();
  int e0 = j * CHUNK;
  for (int e = e0 + t; e < e0 + CHUNK; e += 256) {
    int s = ei[e];
    int d = ei[(size_t)EE + e];
    int b = d / NPB;
    int li = d - b * NPB;
    int pos = atomicAdd(&cur[b], 1);
    tmpb[pos] = (li << 17) | s;
  }
}

// P4: one block per bucket: per-node count/scan/scatter in LDS; coalesced es + offs.
// Also computes per-edge softmax numerators ew[slot][4] and per-node reciprocal
// denominators na[node][4] (LDS float atomics).
__global__ __launch_bounds__(256) void k_p4(const int* __restrict__ tmpb,
                                            const int* __restrict__ T,
                                            const int* __restrict__ BaseTmp,
                                            const int* __restrict__ Base,
                                            const float* __restrict__ a,
                                            int* __restrict__ es, int* __restrict__ offs,
                                            float* __restrict__ ew,
                                            float* __restrict__ na) {
  __shared__ int cnt[256];
  __shared__ int cur[NPB];
  __shared__ int stage[CAP];
  __shared__ float ssum[NPB * 4];
  int b = blockIdx.x, t = threadIdx.x;
  if (b == 0 && t == 0) offs[NN] = ETOT;
  int n0 = b * NPB;
  int nloc = NN - n0;
  if (nloc <= 0) return;
  if (nloc > NPB) nloc = NPB;
  int total = T[b];
  int bt = BaseTmp[b], bs = Base[b];
  cnt[t] = (t < nloc) ? 1 : 0;  // self-loop pre-counted
  for (int i = t; i < NPB * 4; i += 256) ssum[i] = 0.f;
  __syncthreads();
  for (int e = t; e < total; e += 256) {
    int u = tmpb[bt + e];
    atomicAdd(&cnt[u >> 17], 1);
  }
  __syncthreads();
  int v = cnt[t];
  __syncthreads();
  for (int off = 1; off < 256; off <<= 1) {
    int tmp = (t >= off) ? cnt[t - off] : 0;
    __syncthreads();
    cnt[t] += tmp;
    __syncthreads();
  }
  int excl = cnt[t] - v;
  if (t < nloc) {
    int node = n0 + t;
    offs[node] = bs + excl;
    cur[t] = excl + 1;
    if (excl < CAP) {
      stage[excl] = node;  // self-loop src first
      float4 asv = *((const float4*)(a + (size_t)node * 8));
      float4 adv = *((const float4*)(a + (size_t)node * 8 + 4));
      float4 w4;
      w4.x = lrelu_exp(asv.x + adv.x); w4.y = lrelu_exp(asv.y + adv.y);
      w4.z = lrelu_exp(asv.z + adv.z); w4.w = lrelu_exp(asv.w + adv.w);
      *((float4*)(ew + (size_t)(bs + excl) * 4)) = w4;
      atomicAdd(&ssum[t * 4 + 0], w4.x); atomicAdd(&ssum[t * 4 + 1], w4.y);
      atomicAdd(&ssum[t * 4 + 2], w4.z); atomicAdd(&ssum[t * 4 + 3], w4.w);
    }
  }
  __syncthreads();
  for (int e = t; e < total; e += 256) {
    int u = tmpb[bt + e];
    int li = u >> 17;
    int src = u & 0x1FFFF;
    int pos = atomicAdd(&cur[li], 1);
    if (pos < CAP) {
      stage[pos] = src;
      float4 asv = *((const float4*)(a + (size_t)src * 8));
      float4 adv = *((const float4*)(a + (size_t)(n0 + li) * 8 + 4));
      float4 w4;
      w4.x = lrelu_exp(asv.x + adv.x); w4.y = lrelu_exp(asv.y + adv.y);
      w4.z = lrelu_exp(asv.z + adv.z); w4.w = lrelu_exp(asv.w + adv.w);
      *((float4*)(ew + (size_t)(bs + pos) * 4)) = w4;
      atomicAdd(&ssum[li * 4 + 0], w4.x); atomicAdd(&ssum[li * 4 + 1], w4.y);
      atomicAdd(&ssum[li * 4 + 2], w4.z); atomicAdd(&ssum[li * 4 + 3], w4.w);
    }
  }
  __syncthreads();
  int btot = total + nloc;
  if (btot > CAP) btot = CAP;
  for (int i = t; i < btot; i += 256) es[bs + i] = stage[i];
  for (int i = t; i < nloc * 4; i += 256)
    na[(size_t)n0 * 4 + i] = 1.f / (ssum[i] + 1e-16f);
}

// one wave per destination node: pure gather+FMA (weights precomputed in P4).
__global__ __launch_bounds__(256) void k_agg(const unsigned short* __restrict__ xwb,
                                             const float* __restrict__ ew,
                                             const float* __restrict__ na,
                                             const int* __restrict__ offs,
                                             const int* __restrict__ es,
                                             const float* __restrict__ bias,
                                             const float* __restrict__ gamma,
                                             const float* __restrict__ beta,
                                             float* __restrict__ out) {
  int lane = threadIdx.x & 63;
  int node = blockIdx.x * 4 + (threadIdx.x >> 6);
  int off0 = offs[node];
  int d = offs[node + 1] - off0;
  int h = lane >> 4;
  int c = lane * 2;
  float rn = na[(size_t)node * 4 + h];

  const unsigned* xp = (const unsigned*)xwb + lane;
  const int* ep = es + off0;
  const float* wp = ew + (size_t)off0 * 4 + h;
  float ax0 = 0.f, ay0 = 0.f, ax1 = 0.f, ay1 = 0.f;

  int j = 0;
  for (; j + 4 <= d; j += 4) {
    int4 sp = *((const int4*)(ep + j));
    float w0 = wp[4 * j];
    float w1 = wp[4 * j + 4];
    float w2 = wp[4 * j + 8];
    float w3 = wp[4 * j + 12];
    unsigned u0 = xp[(unsigned)sp.x * 64u];
    unsigned u1 = xp[(unsigned)sp.y * 64u];
    unsigned u2 = xp[(unsigned)sp.z * 64u];
    unsigned u3 = xp[(unsigned)sp.w * 64u];
    ax0 = fmaf(w0, __uint_as_float(u0 << 16), ax0);
    ay0 = fmaf(w0, __uint_as_float(u0 & 0xffff0000u), ay0);
    ax1 = fmaf(w1, __uint_as_float(u1 << 16), ax1);
    ay1 = fmaf(w1, __uint_as_float(u1 & 0xffff0000u), ay1);
    ax0 = fmaf(w2, __uint_as_float(u2 << 16), ax0);
    ay0 = fmaf(w2, __uint_as_float(u2 & 0xffff0000u), ay0);
    ax1 = fmaf(w3, __uint_as_float(u3 << 16), ax1);
    ay1 = fmaf(w3, __uint_as_float(u3 & 0xffff0000u), ay1);
  }
  for (; j < d; ++j) {
    int s0 = ep[j];
    float w0 = wp[4 * j];
    unsigned u0 = xp[(unsigned)s0 * 64u];
    ax0 = fmaf(w0, __uint_as_float(u0 << 16), ax0);
    ay0 = fmaf(w0, __uint_as_float(u0 & 0xffff0000u), ay0);
  }
  float accx = ax0 + ax1, accy = ay0 + ay1;

  float vx = accx * rn + bias[c];
  float vy = accy * rn + bias[c + 1];
  float sum = vx + vy, sq = vx * vx + vy * vy;
#pragma unroll
  for (int o = 32; o; o >>= 1) {
    sum += __shfl_xor(sum, o);
    sq += __shfl_xor(sq, o);
  }
  float mean = sum * (1.f / 128.f);
  float var = sq * (1.f / 128.f) - mean * mean;
  float rs = rsqrtf(var + 1e-5f);
  float o0 = gamma[c] * (vx - mean) * rs + beta[c];
  float o1 = gamma[c + 1] * (vy - mean) * rs + beta[c + 1];
  float2 ov; ov.x = o0; ov.y = o1;
  *((float2*)(out + (size_t)node * 128 + c)) = ov;
}

extern "C" void kernel_launch(void* const* d_in, const int* in_sizes, int n_in,
                              void* d_out, int out_size, void* d_ws, size_t ws_size,
                              hipStream_t stream) {
  const float* x = (const float*)d_in[0];
  const int* ei = (const int*)d_in[1];  // int32 per harness contract
  const float* W = (const float*)d_in[3];
  const float* att_src = (const float*)d_in[4];
  const float* att_dst = (const float*)d_in[5];
  const float* bias = (const float*)d_in[6];
  const float* gamma = (const float*)d_in[7];
  const float* beta = (const float*)d_in[8];
  float* out = (float*)d_out;

  char* p = (char*)d_ws;
  auto alloc = [&](size_t bytes) -> char* {
    char* r = p;
    p += (bytes + 255) & ~(size_t)255;
    return r;
  };
  unsigned short* xwb = (unsigned short*)alloc((size_t)NN * 128 * 2);  // 25.6 MB
  float* a = (float*)alloc((size_t)NN * 8 * 4);                        // 3.2 MB
  int* es = (int*)alloc((size_t)ETOT * 4);                             // 6.8 MB
  int* offs = (int*)alloc((size_t)(NN + 1) * 4);
  float* ew = (float*)alloc((size_t)ETOT * 4 * 4);                     // 27.2 MB
  float* na = (float*)alloc((size_t)NN * 4 * 4);                       // 1.6 MB
  int* tmpb = (int*)alloc((size_t)EE * 4);                             // 6.4 MB
  int* H = (int*)alloc((size_t)512 * NBUK * 4);                        // 1 MB
  int* R = (int*)alloc((size_t)NBUK * 512 * 4);                        // 1 MB
  int* T = (int*)alloc((size_t)NBUK * 4);
  int* BaseTmp = (int*)alloc((size_t)(NBUK + 1) * 4);
  int* Base = (int*)alloc((size_t)(NBUK + 1) * 4);

  k_gemm<<<(NN + 63) / 64, 256, 0, stream>>>(x, W, xwb);
  k_logit<<<(NN * 4 + 255) / 256, 256, 0, stream>>>(xwb, att_src, att_dst, a);
  k_p1<<<512, 256, 0, stream>>>(ei, H);
  k_s1<<<NBUK, 512, 0, stream>>>(H, R, T);
  k_s2<<<1, 512, 0, stream>>>(T, BaseTmp, Base);
  k_p3<<<512, 256, 0, stream>>>(ei, R, BaseTmp, tmpb);
  k_p4<<<NBUK, 256, 0, stream>>>(tmpb, T, BaseTmp, Base, a, es, offs, ew, na);
  k_agg<<<NN / 4, 256, 0, stream>>>(xwb, ew, na, offs, es, bias, gamma, beta, out);
}